// Round 13
// baseline (1492.661 us; speedup 1.0000x reference)
//
#include <hip/hip_runtime.h>
#include <hip/hip_bf16.h>

// ---------------------------------------------------------------------------
// VisionMamba, round 12: kill u/dt/bc round-trips; single-barrier gemm_in.
// B=8, L=196, D_MODEL=192, D_INNER=384, D_STATE=16, DT_RANK=12, DEPTH=24.
//
// R12 changes (R11 base, best=1421us):
//  - conv_xproj writes ONLY xdbl[tok][44] (276KB). u/dtg/bc arrays gone.
//  - scan recomputes u for its 16 channels inline (depthwise conv is
//    per-channel => block-local; 3-token halo staged), computes dt from xdbl
//    during staging (12 float4 weight regs preloaded). Bitwise-same formulas.
//  - gemm_in: full K=192 staged in LDS once (2x25.6KB, stride-200 shorts,
//    2-way banks=free) -> ONE barrier per block instead of 12.
// ---------------------------------------------------------------------------

#define NTOK   1568   // B * L
#define DMODEL 192
#define DINNER 384
#define DSTATE 16
#define DTRANK 12
#define DEPTH  24
#define LSEQ   196
#define TCH    49     // scan time-chunk (196 = 4*49)
#define LDA    40     // gemm_ln LDS row stride (bf16)
#define LDK    200    // gemm_in LDS row stride (bf16), 400B -> 2-way banks

typedef __attribute__((ext_vector_type(8))) short short8;
typedef __attribute__((ext_vector_type(4))) short short4v;
typedef __attribute__((ext_vector_type(4))) float floatx4;

__device__ inline short f2bf(float f) {
    __hip_bfloat16 h = __float2bfloat16(f);
    return *reinterpret_cast<short*>(&h);
}

// ---------------- merged pre-stage: weight cvt + transposes + im2col ----------------
#define PR1 884736
#define PR2 1327104   // +442368
#define PR3 1363968   // +36864
#define PR4 1769472   // +405504
#define PR5 1880064   // +110592
#define PR6 3084288   // +1204224
__global__ __launch_bounds__(256) void prep(
    const float* __restrict__ inw, const float* __restrict__ outw,
    const float* __restrict__ pew, const float* __restrict__ xpw,
    const float* __restrict__ dtw, const float* __restrict__ x,
    short* __restrict__ w_in, short* __restrict__ w_out,
    short* __restrict__ w_pe, float* __restrict__ xpwT,
    float* __restrict__ dtwT, __hip_bfloat16* __restrict__ patches)
{
    int idx = blockIdx.x * 256 + threadIdx.x;
    if (idx < PR3) {
        float4 v; short* dst;
        if (idx < PR1)      { v = ((const float4*)inw)[idx];        dst = w_in  + (size_t)idx * 4; }
        else if (idx < PR2) { int i = idx - PR1; v = ((const float4*)outw)[i]; dst = w_out + (size_t)i * 4; }
        else                { int i = idx - PR2; v = ((const float4*)pew)[i];  dst = w_pe  + (size_t)i * 4; }
        short4v o;
        o[0] = f2bf(v.x); o[1] = f2bf(v.y); o[2] = f2bf(v.z); o[3] = f2bf(v.w);
        *(short4v*)dst = o;
    } else if (idx < PR4) {
        int i = idx - PR3;                    // xpwT[layer][k][e] = xpw[layer][e][k]
        int layer = i / 16896, rem = i % 16896;
        int k = rem / 44, e = rem % 44;
        xpwT[i] = xpw[(size_t)layer * 16896 + e * 384 + k];
    } else if (idx < PR5) {
        int i = idx - PR4;                    // dtwT[layer][r][d] = dtw[layer][d][r]
        int layer = i / 4608, rem = i % 4608;
        int r = rem / 384, d = rem % 384;
        dtwT[i] = dtw[(size_t)layer * 4608 + d * 12 + r];
    } else if (idx < PR6) {
        int i = idx - PR5;                    // im2col
        int tok = i / 768, e = i % 768;
        int b = tok / LSEQ, l = tok % LSEQ;
        int py = l / 14, px = l % 14;
        int ic = e >> 8, rem = e & 255, ky = rem >> 4, kx = rem & 15;
        patches[i] = __float2bfloat16(x[((b * 3 + ic) * 224 + py * 16 + ky) * 224 + px * 16 + kx]);
    }
}

// ---------------- gemm_in: xz[M,768] = hn[M,192] @ W[768,192]^T ----------------
// Full K staged once (ONE barrier), then 96 MFMAs with free ds_read pipelining.
__global__ __launch_bounds__(256) void gemm_in(
    const __hip_bfloat16* __restrict__ A, const short* __restrict__ Wb,
    float* __restrict__ C, int M, int N)
{
    __shared__ short As[64 * LDK];
    __shared__ short Ws[64 * LDK];
    int tid = threadIdx.x;
    int m0 = blockIdx.x * 64, n0 = blockIdx.y * 64;
    int wv = tid >> 6, lane = tid & 63;
    int fm = lane & 15, q = lane >> 4;
    const short* Ab = (const short*)A;

    for (int i = tid; i < 1536; i += 256) {      // 64 rows x 24 chunks of 8
        int row = i / 24, kcc = (i % 24) * 8;
        int m = m0 + row;
        short8 v = {0,0,0,0,0,0,0,0};
        if (m < M) v = *(const short8*)&Ab[(size_t)m * DMODEL + kcc];
        *(short8*)&As[row * LDK + kcc] = v;
        short8 w = *(const short8*)&Wb[(size_t)(n0 + row) * DMODEL + kcc];
        *(short8*)&Ws[row * LDK + kcc] = w;
    }
    __syncthreads();

    floatx4 acc[4];
#pragma unroll
    for (int nt = 0; nt < 4; ++nt) acc[nt] = (floatx4){0.f, 0.f, 0.f, 0.f};
#pragma unroll
    for (int k = 0; k < 6; ++k) {
        short8 af = *(const short8*)&As[(wv * 16 + fm) * LDK + k * 32 + q * 8];
#pragma unroll
        for (int nt = 0; nt < 4; ++nt) {
            short8 bf = *(const short8*)&Ws[(nt * 16 + fm) * LDK + k * 32 + q * 8];
            acc[nt] = __builtin_amdgcn_mfma_f32_16x16x32_bf16(af, bf, acc[nt], 0, 0, 0);
        }
    }
#pragma unroll
    for (int nt = 0; nt < 4; ++nt) {
        int col = n0 + nt * 16 + fm;
#pragma unroll
        for (int r = 0; r < 4; ++r) {
            int mrow = m0 + wv * 16 + q * 4 + r;
            if (mrow < M) C[(size_t)mrow * N + col] = acc[nt][r];
        }
    }
}

// ---------------- gemm_ln: 16-row tiles, pipelined LDS, fused residual+LN (R11) ----------------
template<int K>
__global__ __launch_bounds__(256) void gemm_ln(
    const __hip_bfloat16* __restrict__ A, const short* __restrict__ Wb,
    const float* __restrict__ bias, float* __restrict__ residual,
    __hip_bfloat16* __restrict__ hn, float* __restrict__ outf,
    const float* __restrict__ lnw, const float* __restrict__ lnb,
    int accumulate)
{
    __shared__ short As[16 * LDA];
    __shared__ short Ws[192 * LDA];
    __shared__ float slw[192], slb[192], sbias[192];
    __shared__ float sS1[4][16], sS2[4][16];
    int tid = threadIdx.x;
    int m0 = blockIdx.x * 16;
    int wv = tid >> 6, lane = tid & 63;
    int fm = lane & 15, q = lane >> 4;
    int wrow = tid >> 2, kc = (tid & 3) * 8;
    if (tid < 192) {
        slw[tid] = lnw[tid];
        slb[tid] = lnb[tid];
        sbias[tid] = bias ? bias[tid] : 0.f;
    }
    const short* Ab = (const short*)A;
    floatx4 acc[3];
#pragma unroll
    for (int j = 0; j < 3; ++j) acc[j] = (floatx4){0.f, 0.f, 0.f, 0.f};

    short8 aR = {0,0,0,0,0,0,0,0};
    short8 wR[3];
    if (tid < 64) aR = *(const short8*)&Ab[(size_t)(m0 + (tid >> 2)) * K + kc];
#pragma unroll
    for (int j = 0; j < 3; ++j)
        wR[j] = *(const short8*)&Wb[(size_t)(wrow + 64 * j) * K + kc];

    for (int k0 = 0; k0 < K; k0 += 32) {
        if (tid < 64) *(short8*)&As[(tid >> 2) * LDA + kc] = aR;
#pragma unroll
        for (int j = 0; j < 3; ++j)
            *(short8*)&Ws[(wrow + 64 * j) * LDA + kc] = wR[j];
        __syncthreads();
        int kn = k0 + 32;
        if (kn < K) {
            if (tid < 64) aR = *(const short8*)&Ab[(size_t)(m0 + (tid >> 2)) * K + kn + kc];
#pragma unroll
            for (int j = 0; j < 3; ++j)
                wR[j] = *(const short8*)&Wb[(size_t)(wrow + 64 * j) * K + kn + kc];
        }
        short8 af = *(const short8*)&As[fm * LDA + q * 8];
#pragma unroll
        for (int j = 0; j < 3; ++j) {
            int ct = wv * 3 + j;
            short8 bf = *(const short8*)&Ws[(ct * 16 + fm) * LDA + q * 8];
            acc[j] = __builtin_amdgcn_mfma_f32_16x16x32_bf16(af, bf, acc[j], 0, 0, 0);
        }
        __syncthreads();
    }

    float v[3][4];
#pragma unroll
    for (int r = 0; r < 4; ++r) {
        int m = m0 + q * 4 + r;
#pragma unroll
        for (int j = 0; j < 3; ++j) {
            int col = (wv * 3 + j) * 16 + fm;
            float t = acc[j][r] + sbias[col];
            if (accumulate) t += residual[(size_t)m * DMODEL + col];
            v[j][r] = t;
        }
    }
#pragma unroll
    for (int r = 0; r < 4; ++r) {
        int m = m0 + q * 4 + r;
#pragma unroll
        for (int j = 0; j < 3; ++j)
            residual[(size_t)m * DMODEL + (wv * 3 + j) * 16 + fm] = v[j][r];
    }
#pragma unroll
    for (int r = 0; r < 4; ++r) {
        float s1 = v[0][r] + v[1][r] + v[2][r];
        float s2 = v[0][r]*v[0][r] + v[1][r]*v[1][r] + v[2][r]*v[2][r];
        s1 += __shfl_xor(s1, 1); s2 += __shfl_xor(s2, 1);
        s1 += __shfl_xor(s1, 2); s2 += __shfl_xor(s2, 2);
        s1 += __shfl_xor(s1, 4); s2 += __shfl_xor(s2, 4);
        s1 += __shfl_xor(s1, 8); s2 += __shfl_xor(s2, 8);
        if (fm == 0) { sS1[wv][q * 4 + r] = s1; sS2[wv][q * 4 + r] = s2; }
    }
    __syncthreads();
#pragma unroll
    for (int r = 0; r < 4; ++r) {
        int row = q * 4 + r;
        int m = m0 + row;
        float S1 = sS1[0][row] + sS1[1][row] + sS1[2][row] + sS1[3][row];
        float S2 = sS2[0][row] + sS2[1][row] + sS2[2][row] + sS2[3][row];
        float mean = S1 * (1.f / DMODEL);
        float var  = S2 * (1.f / DMODEL) - mean * mean;
        float rstd = rsqrtf(var + 1e-5f);
#pragma unroll
        for (int j = 0; j < 3; ++j) {
            int col = (wv * 3 + j) * 16 + fm;
            float o = (v[j][r] - mean) * rstd * slw[col] + slb[col];
            if (outf) outf[(size_t)m * DMODEL + col] = o;
            else      hn[(size_t)m * DMODEL + col] = __float2bfloat16(o);
        }
    }
}

// ---------------- conv + silu + x_proj -> xdbl only (4 tokens/block) ----------------
__global__ __launch_bounds__(256) void conv_xproj(
    const float* __restrict__ xz, const float* __restrict__ cw,
    const float* __restrict__ cb, const float* __restrict__ xpwT,
    float* __restrict__ xdbl)
{
    __shared__ float sxz[7 * 384];
    __shared__ float su[4 * 384];
    int blk = blockIdx.x;
    int b = blk / 49, c = blk % 49;
    int l0 = c * 4;
    int tid = threadIdx.x;

    for (int idx = tid; idx < 7 * 384; idx += 256) {
        int t = idx / 384, d = idx % 384;
        int l = l0 - 3 + t;
        sxz[idx] = (l >= 0) ? xz[(size_t)(b * LSEQ + l) * 768 + d] : 0.f;
    }
    __syncthreads();

    for (int idx = tid; idx < 4 * 384; idx += 256) {
        int t = idx / 384, d = idx % 384;
        float4 w4 = *(const float4*)&cw[d * 4];
        float acc = cb[d]
            + sxz[t * 384 + d]       * w4.x
            + sxz[(t + 1) * 384 + d] * w4.y
            + sxz[(t + 2) * 384 + d] * w4.z
            + sxz[(t + 3) * 384 + d] * w4.w;
        float sig = 1.f / (1.f + __expf(-acc));
        su[idx] = acc * sig;
    }
    __syncthreads();

    // x_proj: wave wv -> token wv; lane e<44 -> output e; write straight to global
    {
        int wv = tid >> 6, e = tid & 63;
        if (e < 44) {
            float a0 = 0.f, a1 = 0.f, a2 = 0.f, a3 = 0.f;
            const float* ur = &su[wv * 384];
            for (int j = 0; j < 384; j += 4) {
                a0 += ur[j]     * xpwT[(j    ) * 44 + e];
                a1 += ur[j + 1] * xpwT[(j + 1) * 44 + e];
                a2 += ur[j + 2] * xpwT[(j + 2) * 44 + e];
                a3 += ur[j + 3] * xpwT[(j + 3) * 44 + e];
            }
            xdbl[(size_t)(b * LSEQ + l0 + wv) * 44 + e] = (a0 + a1) + (a2 + a3);
        }
    }
}

// ---------------- selective scan: inline u-conv + dt + gating ----------------
#define SPAD 272
__global__ __launch_bounds__(256) void scan_kernel(
    const float* __restrict__ xz, const float* __restrict__ xdbl,
    const float* __restrict__ cw, const float* __restrict__ cb,
    const float* __restrict__ dtwT, const float* __restrict__ dtb,
    const float* __restrict__ Alog, const float* __restrict__ Dp,
    __hip_bfloat16* __restrict__ y)
{
    __shared__ float sxin[52 * 16];
    __shared__ float sdt[TCH][16];
    __shared__ float su_[TCH][16];
    __shared__ float sz_[TCH][16];
    __shared__ float sB_[TCH][16];
    __shared__ float sC_[TCH][16];
    __shared__ float sprod[TCH][SPAD];

    int b  = blockIdx.x / 24;
    int dg = blockIdx.x % 24;
    int tid = threadIdx.x;
    int s = tid & 15, dl = tid >> 4;
    int d = dg * 16 + dl;
    float Ads = -expf(Alog[d * DSTATE + s]);
    float Dd2 = Dp[dg * 16 + (tid & 15)];

    // staging-role preloads: thread (t_=tid>>2, j4=(tid&3)*4) owns channels
    // dg*16+j4 .. +4 for token t_ in every chunk.
    int t_ = tid >> 2, j4 = (tid & 3) * 4;
    float4 wdt[12], dtb4, wc0, wc1, wc2, wc3, cb4;
    if (tid < 196) {
        dtb4 = *(const float4*)&dtb[dg * 16 + j4];
#pragma unroll
        for (int r = 0; r < 12; ++r)
            wdt[r] = *(const float4*)&dtwT[r * 384 + dg * 16 + j4];
        wc0 = *(const float4*)&cw[(dg * 16 + j4 + 0) * 4];
        wc1 = *(const float4*)&cw[(dg * 16 + j4 + 1) * 4];
        wc2 = *(const float4*)&cw[(dg * 16 + j4 + 2) * 4];
        wc3 = *(const float4*)&cw[(dg * 16 + j4 + 3) * 4];
        cb4 = *(const float4*)&cb[dg * 16 + j4];
    }

    float h = 0.f;
    for (int c0 = 0; c0 < LSEQ; c0 += TCH) {
        // stage xin halo rows (52 tokens x 16 channels)
        if (tid < 208) {
            int tt = tid >> 2, jj = (tid & 3) * 4;
            int l = c0 - 3 + tt;
            float4 v = make_float4(0.f, 0.f, 0.f, 0.f);
            if (l >= 0) v = *(const float4*)&xz[(size_t)(b * LSEQ + l) * 768 + dg * 16 + jj];
            *(float4*)&sxin[tt * 16 + jj] = v;
        }
        __syncthreads();

        if (tid < 196) {
            int t = t_;
            size_t tok = (size_t)(b * LSEQ + c0 + t);
            // u = silu(conv) for 4 channels (taps = rows t..t+3 of sxin)
            float4 x0 = *(const float4*)&sxin[(t    ) * 16 + j4];
            float4 x1 = *(const float4*)&sxin[(t + 1) * 16 + j4];
            float4 x2 = *(const float4*)&sxin[(t + 2) * 16 + j4];
            float4 x3 = *(const float4*)&sxin[(t + 3) * 16 + j4];
            float4 uu;
            uu.x = cb4.x + x0.x * wc0.x + x1.x * wc0.y + x2.x * wc0.z + x3.x * wc0.w;
            uu.y = cb4.y + x0.y * wc1.x + x1.y * wc1.y + x2.y * wc1.z + x3.y * wc1.w;
            uu.z = cb4.z + x0.z * wc2.x + x1.z * wc2.y + x2.z * wc2.z + x3.z * wc2.w;
            uu.w = cb4.w + x0.w * wc3.x + x1.w * wc3.y + x2.w * wc3.z + x3.w * wc3.w;
            uu.x = uu.x * (1.f / (1.f + __expf(-uu.x)));
            uu.y = uu.y * (1.f / (1.f + __expf(-uu.y)));
            uu.z = uu.z * (1.f / (1.f + __expf(-uu.z)));
            uu.w = uu.w * (1.f / (1.f + __expf(-uu.w)));
            *(float4*)&su_[t][j4] = uu;
            // dt = softplus(xdbl[:12] . dtw + b)
            float4 xa = *(const float4*)&xdbl[tok * 44 + 0];
            float4 xb = *(const float4*)&xdbl[tok * 44 + 4];
            float4 xc = *(const float4*)&xdbl[tok * 44 + 8];
            float4 a4 = dtb4;
#define ACCR(X, W) { a4.x += (X) * (W).x; a4.y += (X) * (W).y; a4.z += (X) * (W).z; a4.w += (X) * (W).w; }
            ACCR(xa.x, wdt[0]) ACCR(xa.y, wdt[1]) ACCR(xa.z, wdt[2])  ACCR(xa.w, wdt[3])
            ACCR(xb.x, wdt[4]) ACCR(xb.y, wdt[5]) ACCR(xb.z, wdt[6])  ACCR(xb.w, wdt[7])
            ACCR(xc.x, wdt[8]) ACCR(xc.y, wdt[9]) ACCR(xc.z, wdt[10]) ACCR(xc.w, wdt[11])
#undef ACCR
            a4.x = (a4.x > 20.f) ? a4.x : log1pf(__expf(a4.x));
            a4.y = (a4.y > 20.f) ? a4.y : log1pf(__expf(a4.y));
            a4.z = (a4.z > 20.f) ? a4.z : log1pf(__expf(a4.z));
            a4.w = (a4.w > 20.f) ? a4.w : log1pf(__expf(a4.w));
            *(float4*)&sdt[t][j4] = a4;
            // B, C, z
            *(float4*)&sB_[t][j4] = *(const float4*)&xdbl[tok * 44 + 12 + j4];
            *(float4*)&sC_[t][j4] = *(const float4*)&xdbl[tok * 44 + 28 + j4];
            *(float4*)&sz_[t][j4] = *(const float4*)&xz[tok * 768 + DINNER + dg * 16 + j4];
        }
        __syncthreads();

#pragma unroll 7
        for (int t = 0; t < TCH; ++t) {
            float dtv = sdt[t][dl];
            float uv  = su_[t][dl];
            float Bv  = sB_[t][s];
            float Cv  = sC_[t][s];
            float dA  = __expf(dtv * Ads);
            h = dA * h + (dtv * uv) * Bv;
            sprod[t][dl * 17 + s] = h * Cv;
        }
        __syncthreads();

        for (int i = tid; i < TCH * 16; i += 256) {
            int t = i >> 4, dl2 = i & 15;
            float sum = 0.f;
#pragma unroll
            for (int j = 0; j < 16; ++j) sum += sprod[t][dl2 * 17 + j];
            float uv = su_[t][dl2];
            float zv = sz_[t][dl2];
            float sig = 1.f / (1.f + __expf(-zv));
            y[(size_t)(b * LSEQ + c0 + t) * DINNER + dg * 16 + dl2] =
                __float2bfloat16((sum + uv * Dd2) * (zv * sig));
        }
        __syncthreads();
    }
}

// ---------------------------------------------------------------------------
extern "C" void kernel_launch(void* const* d_in, const int* in_sizes, int n_in,
                              void* d_out, int out_size, void* d_ws, size_t ws_size,
                              hipStream_t stream)
{
    const float* x         = (const float*)d_in[0];
    const float* pe_w      = (const float*)d_in[1];
    const float* pe_b      = (const float*)d_in[2];
    const float* norm_w    = (const float*)d_in[3];
    const float* norm_b    = (const float*)d_in[4];
    const float* in_proj_w = (const float*)d_in[5];
    const float* conv_w    = (const float*)d_in[6];
    const float* conv_b    = (const float*)d_in[7];
    const float* xproj_w   = (const float*)d_in[8];
    const float* dtproj_w  = (const float*)d_in[9];
    const float* dtproj_b  = (const float*)d_in[10];
    const float* A_log     = (const float*)d_in[11];
    const float* D_param   = (const float*)d_in[12];
    const float* outproj_w = (const float*)d_in[13];
    const float* normf_w   = (const float*)d_in[14];
    const float* normf_b   = (const float*)d_in[15];

    float* ws = (float*)d_ws;
    float* residual = ws;                                       // 301056 f32
    float* xz       = ws + 301056;                              // 1204224 f32
    float* xdbl     = ws + 1505280;                             // 68992 f32
    __hip_bfloat16* hn      = (__hip_bfloat16*)(ws + 1574272);  // 301056 bf16
    __hip_bfloat16* ybf     = (__hip_bfloat16*)(ws + 1724800);  // 602112 bf16
    __hip_bfloat16* patches = (__hip_bfloat16*)(ws + 2025856);  // 1204224 bf16
    short* w_in  = (short*)(ws + 2627968);                      // 3538944 bf16
    short* w_out = (short*)(ws + 4397440);                      // 1769472 bf16
    short* w_pe  = (short*)(ws + 5282176);                      // 147456 bf16
    float* xpwT  = ws + 5355904;                                // 405504 f32
    float* dtwT  = ws + 5761408;                                // 110592 f32

    prep<<<12048, 256, 0, stream>>>(
        in_proj_w, outproj_w, pe_w, xproj_w, dtproj_w, x,
        w_in, w_out, w_pe, xpwT, dtwT, patches);
    gemm_ln<768><<<98, 256, 0, stream>>>(
        patches, w_pe, pe_b, residual, hn, nullptr, norm_w, norm_b, 0);

    for (int i = 0; i < DEPTH; ++i) {
        int last = (i == DEPTH - 1);
        gemm_in<<<dim3(25, 12), 256, 0, stream>>>(
            hn, w_in + (size_t)i * 768 * DMODEL, xz, NTOK, 768);
        conv_xproj<<<392, 256, 0, stream>>>(
            xz, conv_w + (size_t)i * DINNER * 4, conv_b + (size_t)i * DINNER,
            xpwT + (size_t)i * 384 * 44, xdbl);
        scan_kernel<<<192, 256, 0, stream>>>(
            xz, xdbl, conv_w + (size_t)i * DINNER * 4, conv_b + (size_t)i * DINNER,
            dtwT + (size_t)i * 12 * 384, dtproj_b + (size_t)i * DINNER,
            A_log + (size_t)i * DINNER * DSTATE, D_param + (size_t)i * DINNER, ybf);
        gemm_ln<384><<<98, 256, 0, stream>>>(
            ybf, w_out + (size_t)i * DMODEL * DINNER, nullptr, residual, hn,
            last ? (float*)d_out : nullptr,
            last ? normf_w : norm_w + (i + 1) * DMODEL,
            last ? normf_b : norm_b + (i + 1) * DMODEL,
            1);
    }
}

// Round 14
// 1426.900 us; speedup vs baseline: 1.0461x; 1.0461x over previous
//
#include <hip/hip_runtime.h>
#include <hip/hip_bf16.h>

// ---------------------------------------------------------------------------
// VisionMamba, round 13: R11 baseline (best, 1421us) + single-barrier gemm_in.
// B=8, L=196, D_MODEL=192, D_INNER=384, D_STATE=16, DT_RANK=12, DEPTH=24.
//
// R13: R12 bundled two changes and regressed (scan staging became a serial
// compute stage with scattered xdbl reads). This round: revert to R11
// verbatim, apply ONLY R12's gemm_in (full K=192 staged once in LDS at
// stride-200, ONE barrier instead of 12, then 96 MFMAs with uninterrupted
// ds_read pipelining). Clean attribution.
// ---------------------------------------------------------------------------

#define NTOK   1568   // B * L
#define DMODEL 192
#define DINNER 384
#define DSTATE 16
#define DTRANK 12
#define DEPTH  24
#define LSEQ   196
#define TCH    49     // scan time-chunk (196 = 4*49)
#define LDA    40     // gemm_ln LDS row stride (bf16)
#define LDK    200    // gemm_in LDS row stride (bf16), 400B -> 2-way banks

typedef __attribute__((ext_vector_type(8))) short short8;
typedef __attribute__((ext_vector_type(4))) short short4v;
typedef __attribute__((ext_vector_type(4))) float floatx4;

__device__ inline short f2bf(float f) {
    __hip_bfloat16 h = __float2bfloat16(f);
    return *reinterpret_cast<short*>(&h);
}

// ---------------- merged pre-stage: weight cvt + transposes + im2col ----------------
#define PR1 884736
#define PR2 1327104   // +442368
#define PR3 1363968   // +36864
#define PR4 1769472   // +405504
#define PR5 1880064   // +110592
#define PR6 3084288   // +1204224
__global__ __launch_bounds__(256) void prep(
    const float* __restrict__ inw, const float* __restrict__ outw,
    const float* __restrict__ pew, const float* __restrict__ xpw,
    const float* __restrict__ dtw, const float* __restrict__ x,
    short* __restrict__ w_in, short* __restrict__ w_out,
    short* __restrict__ w_pe, float* __restrict__ xpwT,
    float* __restrict__ dtwT, __hip_bfloat16* __restrict__ patches)
{
    int idx = blockIdx.x * 256 + threadIdx.x;
    if (idx < PR3) {
        float4 v; short* dst;
        if (idx < PR1)      { v = ((const float4*)inw)[idx];        dst = w_in  + (size_t)idx * 4; }
        else if (idx < PR2) { int i = idx - PR1; v = ((const float4*)outw)[i]; dst = w_out + (size_t)i * 4; }
        else                { int i = idx - PR2; v = ((const float4*)pew)[i];  dst = w_pe  + (size_t)i * 4; }
        short4v o;
        o[0] = f2bf(v.x); o[1] = f2bf(v.y); o[2] = f2bf(v.z); o[3] = f2bf(v.w);
        *(short4v*)dst = o;
    } else if (idx < PR4) {
        int i = idx - PR3;                    // xpwT[layer][k][e] = xpw[layer][e][k]
        int layer = i / 16896, rem = i % 16896;
        int k = rem / 44, e = rem % 44;
        xpwT[i] = xpw[(size_t)layer * 16896 + e * 384 + k];
    } else if (idx < PR5) {
        int i = idx - PR4;                    // dtwT[layer][r][d] = dtw[layer][d][r]
        int layer = i / 4608, rem = i % 4608;
        int r = rem / 384, d = rem % 384;
        dtwT[i] = dtw[(size_t)layer * 4608 + d * 12 + r];
    } else if (idx < PR6) {
        int i = idx - PR5;                    // im2col
        int tok = i / 768, e = i % 768;
        int b = tok / LSEQ, l = tok % LSEQ;
        int py = l / 14, px = l % 14;
        int ic = e >> 8, rem = e & 255, ky = rem >> 4, kx = rem & 15;
        patches[i] = __float2bfloat16(x[((b * 3 + ic) * 224 + py * 16 + ky) * 224 + px * 16 + kx]);
    }
}

// ---------------- gemm_in: xz[M,768] = hn[M,192] @ W[768,192]^T ----------------
// Full K=192 staged once (ONE barrier), then 96 MFMAs with free ds_read pipelining.
__global__ __launch_bounds__(256) void gemm_in(
    const __hip_bfloat16* __restrict__ A, const short* __restrict__ Wb,
    float* __restrict__ C, int M, int N)
{
    __shared__ short As[64 * LDK];
    __shared__ short Ws[64 * LDK];
    int tid = threadIdx.x;
    int m0 = blockIdx.x * 64, n0 = blockIdx.y * 64;
    int wv = tid >> 6, lane = tid & 63;
    int fm = lane & 15, q = lane >> 4;
    const short* Ab = (const short*)A;

    for (int i = tid; i < 1536; i += 256) {      // 64 rows x 24 chunks of 8
        int row = i / 24, kcc = (i % 24) * 8;
        int m = m0 + row;
        short8 v = {0,0,0,0,0,0,0,0};
        if (m < M) v = *(const short8*)&Ab[(size_t)m * DMODEL + kcc];
        *(short8*)&As[row * LDK + kcc] = v;
        short8 w = *(const short8*)&Wb[(size_t)(n0 + row) * DMODEL + kcc];
        *(short8*)&Ws[row * LDK + kcc] = w;
    }
    __syncthreads();

    floatx4 acc[4];
#pragma unroll
    for (int nt = 0; nt < 4; ++nt) acc[nt] = (floatx4){0.f, 0.f, 0.f, 0.f};
#pragma unroll
    for (int k = 0; k < 6; ++k) {
        short8 af = *(const short8*)&As[(wv * 16 + fm) * LDK + k * 32 + q * 8];
#pragma unroll
        for (int nt = 0; nt < 4; ++nt) {
            short8 bf = *(const short8*)&Ws[(nt * 16 + fm) * LDK + k * 32 + q * 8];
            acc[nt] = __builtin_amdgcn_mfma_f32_16x16x32_bf16(af, bf, acc[nt], 0, 0, 0);
        }
    }
#pragma unroll
    for (int nt = 0; nt < 4; ++nt) {
        int col = n0 + nt * 16 + fm;
#pragma unroll
        for (int r = 0; r < 4; ++r) {
            int mrow = m0 + wv * 16 + q * 4 + r;
            if (mrow < M) C[(size_t)mrow * N + col] = acc[nt][r];
        }
    }
}

// ---------------- gemm_ln: 16-row tiles, pipelined LDS, fused residual+LN ----------------
template<int K>
__global__ __launch_bounds__(256) void gemm_ln(
    const __hip_bfloat16* __restrict__ A, const short* __restrict__ Wb,
    const float* __restrict__ bias, float* __restrict__ residual,
    __hip_bfloat16* __restrict__ hn, float* __restrict__ outf,
    const float* __restrict__ lnw, const float* __restrict__ lnb,
    int accumulate)
{
    __shared__ short As[16 * LDA];
    __shared__ short Ws[192 * LDA];
    __shared__ float slw[192], slb[192], sbias[192];
    __shared__ float sS1[4][16], sS2[4][16];
    int tid = threadIdx.x;
    int m0 = blockIdx.x * 16;
    int wv = tid >> 6, lane = tid & 63;
    int fm = lane & 15, q = lane >> 4;
    int wrow = tid >> 2, kc = (tid & 3) * 8;
    if (tid < 192) {
        slw[tid] = lnw[tid];
        slb[tid] = lnb[tid];
        sbias[tid] = bias ? bias[tid] : 0.f;
    }
    const short* Ab = (const short*)A;
    floatx4 acc[3];
#pragma unroll
    for (int j = 0; j < 3; ++j) acc[j] = (floatx4){0.f, 0.f, 0.f, 0.f};

    short8 aR = {0,0,0,0,0,0,0,0};
    short8 wR[3];
    if (tid < 64) aR = *(const short8*)&Ab[(size_t)(m0 + (tid >> 2)) * K + kc];
#pragma unroll
    for (int j = 0; j < 3; ++j)
        wR[j] = *(const short8*)&Wb[(size_t)(wrow + 64 * j) * K + kc];

    for (int k0 = 0; k0 < K; k0 += 32) {
        if (tid < 64) *(short8*)&As[(tid >> 2) * LDA + kc] = aR;
#pragma unroll
        for (int j = 0; j < 3; ++j)
            *(short8*)&Ws[(wrow + 64 * j) * LDA + kc] = wR[j];
        __syncthreads();
        int kn = k0 + 32;
        if (kn < K) {
            if (tid < 64) aR = *(const short8*)&Ab[(size_t)(m0 + (tid >> 2)) * K + kn + kc];
#pragma unroll
            for (int j = 0; j < 3; ++j)
                wR[j] = *(const short8*)&Wb[(size_t)(wrow + 64 * j) * K + kn + kc];
        }
        short8 af = *(const short8*)&As[fm * LDA + q * 8];
#pragma unroll
        for (int j = 0; j < 3; ++j) {
            int ct = wv * 3 + j;
            short8 bf = *(const short8*)&Ws[(ct * 16 + fm) * LDA + q * 8];
            acc[j] = __builtin_amdgcn_mfma_f32_16x16x32_bf16(af, bf, acc[j], 0, 0, 0);
        }
        __syncthreads();
    }

    float v[3][4];
#pragma unroll
    for (int r = 0; r < 4; ++r) {
        int m = m0 + q * 4 + r;
#pragma unroll
        for (int j = 0; j < 3; ++j) {
            int col = (wv * 3 + j) * 16 + fm;
            float t = acc[j][r] + sbias[col];
            if (accumulate) t += residual[(size_t)m * DMODEL + col];
            v[j][r] = t;
        }
    }
#pragma unroll
    for (int r = 0; r < 4; ++r) {
        int m = m0 + q * 4 + r;
#pragma unroll
        for (int j = 0; j < 3; ++j)
            residual[(size_t)m * DMODEL + (wv * 3 + j) * 16 + fm] = v[j][r];
    }
#pragma unroll
    for (int r = 0; r < 4; ++r) {
        float s1 = v[0][r] + v[1][r] + v[2][r];
        float s2 = v[0][r]*v[0][r] + v[1][r]*v[1][r] + v[2][r]*v[2][r];
        s1 += __shfl_xor(s1, 1); s2 += __shfl_xor(s2, 1);
        s1 += __shfl_xor(s1, 2); s2 += __shfl_xor(s2, 2);
        s1 += __shfl_xor(s1, 4); s2 += __shfl_xor(s2, 4);
        s1 += __shfl_xor(s1, 8); s2 += __shfl_xor(s2, 8);
        if (fm == 0) { sS1[wv][q * 4 + r] = s1; sS2[wv][q * 4 + r] = s2; }
    }
    __syncthreads();
#pragma unroll
    for (int r = 0; r < 4; ++r) {
        int row = q * 4 + r;
        int m = m0 + row;
        float S1 = sS1[0][row] + sS1[1][row] + sS1[2][row] + sS1[3][row];
        float S2 = sS2[0][row] + sS2[1][row] + sS2[2][row] + sS2[3][row];
        float mean = S1 * (1.f / DMODEL);
        float var  = S2 * (1.f / DMODEL) - mean * mean;
        float rstd = rsqrtf(var + 1e-5f);
#pragma unroll
        for (int j = 0; j < 3; ++j) {
            int col = (wv * 3 + j) * 16 + fm;
            float o = (v[j][r] - mean) * rstd * slw[col] + slb[col];
            if (outf) outf[(size_t)m * DMODEL + col] = o;
            else      hn[(size_t)m * DMODEL + col] = __float2bfloat16(o);
        }
    }
}

// ---------------- conv + silu + x_proj + dt : 4 tokens/block (392 blocks) ----------------
__global__ __launch_bounds__(256) void conv_xproj_dt(
    const float* __restrict__ xz, const float* __restrict__ cw,
    const float* __restrict__ cb, const float* __restrict__ xpwT,
    const float* __restrict__ dtwT, const float* __restrict__ dtb,
    float* __restrict__ u, float* __restrict__ dtg, float* __restrict__ bcg)
{
    __shared__ float sxz[7 * 384];
    __shared__ float su[4 * 384];
    __shared__ float sx[4 * 48];
    int blk = blockIdx.x;
    int b = blk / 49, c = blk % 49;
    int l0 = c * 4;
    int tid = threadIdx.x;

    for (int idx = tid; idx < 7 * 384; idx += 256) {
        int t = idx / 384, d = idx % 384;
        int l = l0 - 3 + t;
        sxz[idx] = (l >= 0) ? xz[(size_t)(b * LSEQ + l) * 768 + d] : 0.f;
    }
    __syncthreads();

    for (int idx = tid; idx < 4 * 384; idx += 256) {
        int t = idx / 384, d = idx % 384;
        float4 w4 = *(const float4*)&cw[d * 4];
        float acc = cb[d]
            + sxz[t * 384 + d]       * w4.x
            + sxz[(t + 1) * 384 + d] * w4.y
            + sxz[(t + 2) * 384 + d] * w4.z
            + sxz[(t + 3) * 384 + d] * w4.w;
        float sig = 1.f / (1.f + __expf(-acc));
        float val = acc * sig;
        su[idx] = val;
        u[(size_t)(b * LSEQ + l0 + t) * 384 + d] = val;
    }
    __syncthreads();

    {
        int wv = tid >> 6, e = tid & 63;
        if (e < 44) {
            float a0 = 0.f, a1 = 0.f, a2 = 0.f, a3 = 0.f;
            const float* ur = &su[wv * 384];
            for (int j = 0; j < 384; j += 4) {
                a0 += ur[j]     * xpwT[(j    ) * 44 + e];
                a1 += ur[j + 1] * xpwT[(j + 1) * 44 + e];
                a2 += ur[j + 2] * xpwT[(j + 2) * 44 + e];
                a3 += ur[j + 3] * xpwT[(j + 3) * 44 + e];
            }
            sx[wv * 48 + e] = (a0 + a1) + (a2 + a3);
        }
    }
    __syncthreads();

    for (int idx = tid; idx < 4 * 384; idx += 256) {
        int t = idx / 384, d = idx % 384;
        float acc = dtb[d];
#pragma unroll
        for (int r = 0; r < DTRANK; ++r) acc += sx[t * 48 + r] * dtwT[r * 384 + d];
        float sp = (acc > 20.f) ? acc : log1pf(__expf(acc));
        dtg[(size_t)(b * LSEQ + l0 + t) * 384 + d] = sp;
    }
    if (tid < 128) {
        int t = tid >> 5, j = tid & 31;
        bcg[(size_t)(b * LSEQ + l0 + t) * 32 + j] = sx[t * 48 + 12 + j];
    }
}

// ---------------- selective scan + gating (3-phase, R7/R11) ----------------
#define SPAD 272
__global__ __launch_bounds__(256) void scan_kernel(
    const float* __restrict__ u, const float* __restrict__ dtg,
    const float* __restrict__ bc, const float* __restrict__ xz,
    const float* __restrict__ Alog, const float* __restrict__ Dp,
    __hip_bfloat16* __restrict__ y)
{
    __shared__ float sdt[TCH][16];
    __shared__ float su_[TCH][16];
    __shared__ float sz_[TCH][16];
    __shared__ float sB_[TCH][16];
    __shared__ float sC_[TCH][16];
    __shared__ float sprod[TCH][SPAD];

    int b  = blockIdx.x / 24;
    int dg = blockIdx.x % 24;
    int tid = threadIdx.x;
    int s = tid & 15, dl = tid >> 4;
    int d = dg * 16 + dl;
    float Ads = -expf(Alog[d * DSTATE + s]);
    float Dd2 = Dp[dg * 16 + (tid & 15)];
    float h = 0.f;

    for (int c0 = 0; c0 < LSEQ; c0 += TCH) {
        if (tid < TCH * 4) {
            int t = tid >> 2, j4 = (tid & 3) * 4;
            size_t tok = (size_t)(b * LSEQ + c0 + t);
            *(float4*)&sdt[t][j4] = *(const float4*)&dtg[tok * DINNER + dg * 16 + j4];
            *(float4*)&su_[t][j4] = *(const float4*)&u  [tok * DINNER + dg * 16 + j4];
            *(float4*)&sz_[t][j4] = *(const float4*)&xz [tok * 768 + DINNER + dg * 16 + j4];
            *(float4*)&sB_[t][j4] = *(const float4*)&bc [tok * 32 + j4];
            *(float4*)&sC_[t][j4] = *(const float4*)&bc [tok * 32 + 16 + j4];
        }
        __syncthreads();

#pragma unroll 7
        for (int t = 0; t < TCH; ++t) {
            float dtv = sdt[t][dl];
            float uv  = su_[t][dl];
            float Bv  = sB_[t][s];
            float Cv  = sC_[t][s];
            float dA  = __expf(dtv * Ads);
            h = dA * h + (dtv * uv) * Bv;
            sprod[t][dl * 17 + s] = h * Cv;
        }
        __syncthreads();

        for (int i = tid; i < TCH * 16; i += 256) {
            int t = i >> 4, dl2 = i & 15;
            float sum = 0.f;
#pragma unroll
            for (int j = 0; j < 16; ++j) sum += sprod[t][dl2 * 17 + j];
            float uv = su_[t][dl2];
            float zv = sz_[t][dl2];
            float sig = 1.f / (1.f + __expf(-zv));
            y[(size_t)(b * LSEQ + c0 + t) * DINNER + dg * 16 + dl2] =
                __float2bfloat16((sum + uv * Dd2) * (zv * sig));
        }
        __syncthreads();
    }
}

// ---------------------------------------------------------------------------
extern "C" void kernel_launch(void* const* d_in, const int* in_sizes, int n_in,
                              void* d_out, int out_size, void* d_ws, size_t ws_size,
                              hipStream_t stream)
{
    const float* x         = (const float*)d_in[0];
    const float* pe_w      = (const float*)d_in[1];
    const float* pe_b      = (const float*)d_in[2];
    const float* norm_w    = (const float*)d_in[3];
    const float* norm_b    = (const float*)d_in[4];
    const float* in_proj_w = (const float*)d_in[5];
    const float* conv_w    = (const float*)d_in[6];
    const float* conv_b    = (const float*)d_in[7];
    const float* xproj_w   = (const float*)d_in[8];
    const float* dtproj_w  = (const float*)d_in[9];
    const float* dtproj_b  = (const float*)d_in[10];
    const float* A_log     = (const float*)d_in[11];
    const float* D_param   = (const float*)d_in[12];
    const float* outproj_w = (const float*)d_in[13];
    const float* normf_w   = (const float*)d_in[14];
    const float* normf_b   = (const float*)d_in[15];

    float* ws = (float*)d_ws;
    float* residual = ws;                       // 301056 f32
    float* xz       = residual + 301056;        // 1204224 f32
    float* ubuf     = xz + 1204224;             // 602112 f32
    float* dtbuf    = ubuf + 602112;            // 602112 f32
    float* bcbuf    = dtbuf + 602112;           // 50176 f32
    __hip_bfloat16* hn      = (__hip_bfloat16*)(ws + 2759680);  // 301056 bf16
    __hip_bfloat16* ybf     = (__hip_bfloat16*)(ws + 2910208);  // 602112 bf16
    __hip_bfloat16* patches = (__hip_bfloat16*)(ws + 3211264);  // 1204224 bf16
    short* w_in  = (short*)(ws + 3813376);      // 3538944 bf16
    short* w_out = (short*)(ws + 5582848);      // 1769472 bf16
    short* w_pe  = (short*)(ws + 6467584);      // 147456 bf16
    float* xpwT  = ws + 6541312;                // 405504 f32
    float* dtwT  = xpwT + 405504;               // 110592 f32

    prep<<<12048, 256, 0, stream>>>(
        in_proj_w, outproj_w, pe_w, xproj_w, dtproj_w, x,
        w_in, w_out, w_pe, xpwT, dtwT, patches);
    gemm_ln<768><<<98, 256, 0, stream>>>(
        patches, w_pe, pe_b, residual, hn, nullptr, norm_w, norm_b, 0);

    for (int i = 0; i < DEPTH; ++i) {
        int last = (i == DEPTH - 1);
        gemm_in<<<dim3(25, 12), 256, 0, stream>>>(
            hn, w_in + (size_t)i * 768 * DMODEL, xz, NTOK, 768);
        conv_xproj_dt<<<392, 256, 0, stream>>>(
            xz, conv_w + (size_t)i * DINNER * 4, conv_b + (size_t)i * DINNER,
            xpwT + (size_t)i * 384 * 44, dtwT + (size_t)i * 12 * 384,
            dtproj_b + (size_t)i * DINNER, ubuf, dtbuf, bcbuf);
        scan_kernel<<<192, 256, 0, stream>>>(
            ubuf, dtbuf, bcbuf, xz, A_log + (size_t)i * DINNER * DSTATE,
            D_param + (size_t)i * DINNER, ybf);
        gemm_ln<384><<<98, 256, 0, stream>>>(
            ybf, w_out + (size_t)i * DMODEL * DINNER, nullptr, residual, hn,
            last ? (float*)d_out : nullptr,
            last ? normf_w : norm_w + (i + 1) * DMODEL,
            last ? normf_b : norm_b + (i + 1) * DMODEL,
            1);
    }
}